// Round 2
// baseline (1798.590 us; speedup 1.0000x reference)
//
#include <hip/hip_runtime.h>

#define N_NODES 100000
#define N_EDGES 1600000
#define D_IN 64
#define D_HID 128

// ---------------- Kernel A: agg = x (fold the "+x" of GIN into the init) ----
__global__ __launch_bounds__(256) void k_init_agg(const float4* __restrict__ x,
                                                  float4* __restrict__ agg) {
    int i = blockIdx.x * 256 + threadIdx.x;   // grid sized exactly: 1.6M float4
    agg[i] = x[i];
}

// ---------------- Kernel B: scatter-add x[src] into agg[dst] ----------------
// 16 threads per edge, each handles a float4 (4 cols) -> 4 f32 atomics.
__global__ __launch_bounds__(256) void k_scatter(const int* __restrict__ src,
                                                 const int* __restrict__ dst,
                                                 const float4* __restrict__ x,
                                                 float* __restrict__ agg) {
    int tid = blockIdx.x * 256 + threadIdx.x;
    int e = tid >> 4;
    int q = tid & 15;
    int s = src[e];
    int d = dst[e];
    float4 v = x[(size_t)s * 16 + q];
    float* a = agg + (size_t)d * 64 + q * 4;
    unsafeAtomicAdd(a + 0, v.x);
    unsafeAtomicAdd(a + 1, v.y);
    unsafeAtomicAdd(a + 2, v.z);
    unsafeAtomicAdd(a + 3, v.w);
}

// ---------------- Kernel C: h1 = relu(agg @ W1 + b1) ------------------------
// 64 rows/block, W1 (64x128) fully in LDS (32KB) + A tile (64x64, 16KB).
__global__ __launch_bounds__(256) void k_gemm1(const float* __restrict__ A,
                                               const float* __restrict__ W,
                                               const float* __restrict__ bias,
                                               float* __restrict__ H) {
    __shared__ float Wl[64 * 128];
    __shared__ float Al[64 * 64];
    int tid = threadIdx.x;
    for (int i = tid; i < 2048; i += 256)
        ((float4*)Wl)[i] = ((const float4*)W)[i];
    int m0 = blockIdx.x * 64;
    for (int i = tid; i < 1024; i += 256) {
        int r = i >> 4;
        int gr = m0 + r;
        float4 v = (gr < N_NODES) ? ((const float4*)A)[(size_t)gr * 16 + (i & 15)]
                                  : make_float4(0.f, 0.f, 0.f, 0.f);
        ((float4*)Al)[i] = v;
    }
    __syncthreads();

    int tx = tid & 31, ty = tid >> 5;
    int r0 = ty * 8, c0 = tx * 4;
    float acc[8][4] = {};
#pragma unroll
    for (int k4 = 0; k4 < 16; ++k4) {
        float4 b0 = *(const float4*)&Wl[(4 * k4 + 0) * 128 + c0];
        float4 b1 = *(const float4*)&Wl[(4 * k4 + 1) * 128 + c0];
        float4 b2 = *(const float4*)&Wl[(4 * k4 + 2) * 128 + c0];
        float4 b3 = *(const float4*)&Wl[(4 * k4 + 3) * 128 + c0];
#pragma unroll
        for (int i = 0; i < 8; ++i) {
            float4 a = *(const float4*)&Al[(r0 + i) * 64 + 4 * k4];
            acc[i][0] += a.x * b0.x + a.y * b1.x + a.z * b2.x + a.w * b3.x;
            acc[i][1] += a.x * b0.y + a.y * b1.y + a.z * b2.y + a.w * b3.y;
            acc[i][2] += a.x * b0.z + a.y * b1.z + a.z * b2.z + a.w * b3.z;
            acc[i][3] += a.x * b0.w + a.y * b1.w + a.z * b2.w + a.w * b3.w;
        }
    }
    float4 bb = *(const float4*)&bias[c0];
#pragma unroll
    for (int i = 0; i < 8; ++i) {
        int gr = m0 + r0 + i;
        if (gr < N_NODES) {
            float4 o;
            o.x = fmaxf(acc[i][0] + bb.x, 0.f);
            o.y = fmaxf(acc[i][1] + bb.y, 0.f);
            o.z = fmaxf(acc[i][2] + bb.z, 0.f);
            o.w = fmaxf(acc[i][3] + bb.w, 0.f);
            ((float4*)H)[(size_t)gr * 32 + tx] = o;
        }
    }
}

// ---------------- Kernel D: out = relu(h1 @ W2 + b2); fused BN partial stats
// 32 rows/block (exactly 3125 blocks). Dynamic LDS: W2 64KB + A tile 16KB.
__global__ __launch_bounds__(256) void k_gemm2(const float* __restrict__ A,
                                               const float* __restrict__ W,
                                               const float* __restrict__ bias,
                                               float* __restrict__ OUT,
                                               float* __restrict__ stats) {
    extern __shared__ float lds[];
    float* Wl = lds;            // 128*128
    float* Al = lds + 16384;    // 32*128
    int tid = threadIdx.x;
    for (int i = tid; i < 4096; i += 256)
        ((float4*)Wl)[i] = ((const float4*)W)[i];
    int m0 = blockIdx.x * 32;
    for (int i = tid; i < 1024; i += 256) {
        int r = i >> 5;
        ((float4*)Al)[i] = ((const float4*)A)[(size_t)(m0 + r) * 32 + (i & 31)];
    }
    __syncthreads();

    int tx = tid & 31, ty = tid >> 5;
    int r0 = ty * 4, c0 = tx * 4;
    float acc[4][4] = {};
#pragma unroll 8
    for (int k4 = 0; k4 < 32; ++k4) {
        float4 b0 = *(const float4*)&Wl[(4 * k4 + 0) * 128 + c0];
        float4 b1 = *(const float4*)&Wl[(4 * k4 + 1) * 128 + c0];
        float4 b2 = *(const float4*)&Wl[(4 * k4 + 2) * 128 + c0];
        float4 b3 = *(const float4*)&Wl[(4 * k4 + 3) * 128 + c0];
#pragma unroll
        for (int i = 0; i < 4; ++i) {
            float4 a = *(const float4*)&Al[(r0 + i) * 128 + 4 * k4];
            acc[i][0] += a.x * b0.x + a.y * b1.x + a.z * b2.x + a.w * b3.x;
            acc[i][1] += a.x * b0.y + a.y * b1.y + a.z * b2.y + a.w * b3.y;
            acc[i][2] += a.x * b0.z + a.y * b1.z + a.z * b2.z + a.w * b3.z;
            acc[i][3] += a.x * b0.w + a.y * b1.w + a.z * b2.w + a.w * b3.w;
        }
    }
    float4 bb = *(const float4*)&bias[c0];
    float s[4] = {0.f, 0.f, 0.f, 0.f};
    float q[4] = {0.f, 0.f, 0.f, 0.f};
#pragma unroll
    for (int i = 0; i < 4; ++i) {
        float4 o;
        o.x = fmaxf(acc[i][0] + bb.x, 0.f);
        o.y = fmaxf(acc[i][1] + bb.y, 0.f);
        o.z = fmaxf(acc[i][2] + bb.z, 0.f);
        o.w = fmaxf(acc[i][3] + bb.w, 0.f);
        ((float4*)OUT)[(size_t)(m0 + r0 + i) * 32 + tx] = o;
        s[0] += o.x; q[0] += o.x * o.x;
        s[1] += o.y; q[1] += o.y * o.y;
        s[2] += o.z; q[2] += o.z * o.z;
        s[3] += o.w; q[3] += o.w * o.w;
    }
    __syncthreads();                 // done reading Al; reuse as reduction buf
    float* red = Al;                 // need 2048 floats, have 4096
    *(float4*)&red[ty * 128 + c0] = make_float4(s[0], s[1], s[2], s[3]);
    *(float4*)&red[1024 + ty * 128 + c0] = make_float4(q[0], q[1], q[2], q[3]);
    __syncthreads();
    if (tid < 128) {
        float ss = 0.f, sq = 0.f;
#pragma unroll
        for (int g = 0; g < 8; ++g) {
            ss += red[g * 128 + tid];
            sq += red[1024 + g * 128 + tid];
        }
        unsafeAtomicAdd(&stats[tid], ss);
        unsafeAtomicAdd(&stats[128 + tid], sq);
    }
}

// ---------------- Kernel E: per-channel scale/shift from stats --------------
__global__ void k_finalize(const float* __restrict__ stats,
                           const float* __restrict__ gamma,
                           const float* __restrict__ beta,
                           float* __restrict__ ss) {
    int c = threadIdx.x;
    float mean = stats[c] * (1.0f / N_NODES);
    float var = stats[128 + c] * (1.0f / N_NODES) - mean * mean;
    float scale = gamma[c] * rsqrtf(var + 1e-5f);
    ss[c] = scale;
    ss[128 + c] = beta[c] - mean * scale;
}

// ---------------- Kernel F: in-place normalize ------------------------------
__global__ __launch_bounds__(256) void k_bn(float4* __restrict__ out,
                                            const float4* __restrict__ ss) {
    int stride = gridDim.x * 256;
    for (int f = blockIdx.x * 256 + threadIdx.x; f < N_NODES * 32; f += stride) {
        int c4 = f & 31;
        float4 sc = ss[c4];
        float4 sh = ss[32 + c4];
        float4 v = out[f];
        v.x = v.x * sc.x + sh.x;
        v.y = v.y * sc.y + sh.y;
        v.z = v.z * sc.z + sh.z;
        v.w = v.w * sc.w + sh.w;
        out[f] = v;
    }
}

extern "C" void kernel_launch(void* const* d_in, const int* in_sizes, int n_in,
                              void* d_out, int out_size, void* d_ws, size_t ws_size,
                              hipStream_t stream) {
    const float* x     = (const float*)d_in[0];
    const int*   ei    = (const int*)d_in[1];
    const float* W1    = (const float*)d_in[2];
    const float* b1    = (const float*)d_in[3];
    const float* W2    = (const float*)d_in[4];
    const float* b2    = (const float*)d_in[5];
    const float* gamma = (const float*)d_in[6];
    const float* beta  = (const float*)d_in[7];
    float* out = (float*)d_out;

    float* agg   = (float*)d_ws;                       // 100000*64
    float* h1    = agg + (size_t)N_NODES * D_IN;       // 100000*128
    float* stats = h1 + (size_t)N_NODES * D_HID;       // 256
    float* ss    = stats + 256;                        // 256

    const int* src = ei;
    const int* dst = ei + N_EDGES;

    k_init_agg<<<N_NODES * D_IN / 4 / 256, 256, 0, stream>>>((const float4*)x, (float4*)agg);
    k_scatter<<<(size_t)N_EDGES * 16 / 256, 256, 0, stream>>>(src, dst, (const float4*)x, agg);
    k_gemm1<<<(N_NODES + 63) / 64, 256, 0, stream>>>(agg, W1, b1, h1);
    (void)hipMemsetAsync(stats, 0, 256 * sizeof(float), stream);
    k_gemm2<<<N_NODES / 32, 256, 80 * 1024, stream>>>(h1, W2, b2, out, stats);
    k_finalize<<<1, 128, 0, stream>>>(stats, gamma, beta, ss);
    k_bn<<<2048, 256, 0, stream>>>((float4*)out, (const float4*)ss);
}

// Round 5
// 695.324 us; speedup vs baseline: 2.5867x; 2.5867x over previous
//
#include <hip/hip_runtime.h>

#define N_NODES 100000
#define N_EDGES 1600000
#define D_IN 64
#define D_HID 128

// ============ CSR build ============
__global__ __launch_bounds__(256) void k_hist(const int* __restrict__ dst,
                                              int* __restrict__ counts) {
    int e = blockIdx.x * 256 + threadIdx.x;   // grid = exactly N_EDGES threads
    atomicAdd(&counts[dst[e]], 1);
}

// Scan phase 1: each block scans 1024 counts (4/thread), writes local
// exclusive scan + block total.
__global__ __launch_bounds__(256) void k_scan1(const int* __restrict__ counts,
                                               int* __restrict__ loc,
                                               int* __restrict__ bsum) {
    __shared__ int tmp[256];
    int t = threadIdx.x;
    int base = blockIdx.x * 1024 + t * 4;
    int v0 = (base + 0 < N_NODES) ? counts[base + 0] : 0;
    int v1 = (base + 1 < N_NODES) ? counts[base + 1] : 0;
    int v2 = (base + 2 < N_NODES) ? counts[base + 2] : 0;
    int v3 = (base + 3 < N_NODES) ? counts[base + 3] : 0;
    tmp[t] = v0 + v1 + v2 + v3;
    __syncthreads();
    for (int off = 1; off < 256; off <<= 1) {
        int val = tmp[t];
        int add = (t >= off) ? tmp[t - off] : 0;
        __syncthreads();
        tmp[t] = val + add;
        __syncthreads();
    }
    int excl = t ? tmp[t - 1] : 0;
    if (base + 0 < N_NODES) loc[base + 0] = excl;
    if (base + 1 < N_NODES) loc[base + 1] = excl + v0;
    if (base + 2 < N_NODES) loc[base + 2] = excl + v0 + v1;
    if (base + 3 < N_NODES) loc[base + 3] = excl + v0 + v1 + v2;
    if (t == 255) bsum[blockIdx.x] = tmp[255];
}

// Scan phase 2: single block scans the 98 block totals (exclusive).
__global__ void k_scan2(const int* __restrict__ bsum, int* __restrict__ bpref) {
    __shared__ int tmp[128];
    int t = threadIdx.x;             // 128 threads
    tmp[t] = (t < 98) ? bsum[t] : 0;
    __syncthreads();
    for (int off = 1; off < 128; off <<= 1) {
        int val = tmp[t];
        int add = (t >= off) ? tmp[t - off] : 0;
        __syncthreads();
        tmp[t] = val + add;
        __syncthreads();
    }
    bpref[t] = t ? tmp[t - 1] : 0;
}

// Scan phase 3: global exclusive offsets.
__global__ __launch_bounds__(256) void k_scan3(const int* __restrict__ loc,
                                               const int* __restrict__ bpref,
                                               int* __restrict__ offs) {
    int i = blockIdx.x * 256 + threadIdx.x;
    if (i < N_NODES) offs[i] = loc[i] + bpref[i >> 10];
}

// Fill: place src ids into per-dst buckets; offs[] acts as cursor and ends
// at bucket END afterwards (start recovered via counts).
__global__ __launch_bounds__(256) void k_fill(const int* __restrict__ src,
                                              const int* __restrict__ dst,
                                              int* __restrict__ offs,
                                              int* __restrict__ srcs) {
    int e = blockIdx.x * 256 + threadIdx.x;   // grid = exactly N_EDGES threads
    int p = atomicAdd(&offs[dst[e]], 1);
    srcs[p] = src[e];
}

// Gather: one wave per node, lane = feature column. agg = x[self] + sum x[src].
__global__ __launch_bounds__(256) void k_gather(const float* __restrict__ x,
                                                const int* __restrict__ offs_end,
                                                const int* __restrict__ counts,
                                                const int* __restrict__ srcs,
                                                float* __restrict__ agg) {
    int wid = (blockIdx.x * 256 + threadIdx.x) >> 6;   // 100000 waves exactly
    int lane = threadIdx.x & 63;
    int end = offs_end[wid];
    int beg = end - counts[wid];
    float sum = x[(size_t)wid * 64 + lane];
    int e = beg;
    for (; e + 4 <= end; e += 4) {
        int s0 = srcs[e], s1 = srcs[e + 1], s2 = srcs[e + 2], s3 = srcs[e + 3];
        float a0 = x[(size_t)s0 * 64 + lane];
        float a1 = x[(size_t)s1 * 64 + lane];
        float a2 = x[(size_t)s2 * 64 + lane];
        float a3 = x[(size_t)s3 * 64 + lane];
        sum += a0 + a1 + a2 + a3;
    }
    for (; e < end; ++e) sum += x[(size_t)srcs[e] * 64 + lane];
    agg[(size_t)wid * 64 + lane] = sum;
}

// ============ Kernel C: h1 = relu(agg @ W1 + b1) ============
__global__ __launch_bounds__(256) void k_gemm1(const float* __restrict__ A,
                                               const float* __restrict__ W,
                                               const float* __restrict__ bias,
                                               float* __restrict__ H) {
    __shared__ float Wl[64 * 128];
    __shared__ float Al[64 * 64];
    int tid = threadIdx.x;
    for (int i = tid; i < 2048; i += 256)
        ((float4*)Wl)[i] = ((const float4*)W)[i];
    int m0 = blockIdx.x * 64;
    for (int i = tid; i < 1024; i += 256) {
        int r = i >> 4;
        int gr = m0 + r;
        float4 v = (gr < N_NODES) ? ((const float4*)A)[(size_t)gr * 16 + (i & 15)]
                                  : make_float4(0.f, 0.f, 0.f, 0.f);
        ((float4*)Al)[i] = v;
    }
    __syncthreads();

    int tx = tid & 31, ty = tid >> 5;
    int r0 = ty * 8, c0 = tx * 4;
    float acc[8][4] = {};
#pragma unroll
    for (int k4 = 0; k4 < 16; ++k4) {
        float4 b0 = *(const float4*)&Wl[(4 * k4 + 0) * 128 + c0];
        float4 b1 = *(const float4*)&Wl[(4 * k4 + 1) * 128 + c0];
        float4 b2 = *(const float4*)&Wl[(4 * k4 + 2) * 128 + c0];
        float4 b3 = *(const float4*)&Wl[(4 * k4 + 3) * 128 + c0];
#pragma unroll
        for (int i = 0; i < 8; ++i) {
            float4 a = *(const float4*)&Al[(r0 + i) * 64 + 4 * k4];
            acc[i][0] += a.x * b0.x + a.y * b1.x + a.z * b2.x + a.w * b3.x;
            acc[i][1] += a.x * b0.y + a.y * b1.y + a.z * b2.y + a.w * b3.y;
            acc[i][2] += a.x * b0.z + a.y * b1.z + a.z * b2.z + a.w * b3.z;
            acc[i][3] += a.x * b0.w + a.y * b1.w + a.z * b2.w + a.w * b3.w;
        }
    }
    float4 bb = *(const float4*)&bias[c0];
#pragma unroll
    for (int i = 0; i < 8; ++i) {
        int gr = m0 + r0 + i;
        if (gr < N_NODES) {
            float4 o;
            o.x = fmaxf(acc[i][0] + bb.x, 0.f);
            o.y = fmaxf(acc[i][1] + bb.y, 0.f);
            o.z = fmaxf(acc[i][2] + bb.z, 0.f);
            o.w = fmaxf(acc[i][3] + bb.w, 0.f);
            ((float4*)H)[(size_t)gr * 32 + tx] = o;
        }
    }
}

// ============ Kernel D: out = relu(h1 @ W2 + b2) + fused BN partial stats ===
__global__ __launch_bounds__(256) void k_gemm2(const float* __restrict__ A,
                                               const float* __restrict__ W,
                                               const float* __restrict__ bias,
                                               float* __restrict__ OUT,
                                               float* __restrict__ stats) {
    extern __shared__ float lds[];
    float* Wl = lds;            // 128*128
    float* Al = lds + 16384;    // 32*128
    int tid = threadIdx.x;
    for (int i = tid; i < 4096; i += 256)
        ((float4*)Wl)[i] = ((const float4*)W)[i];
    int m0 = blockIdx.x * 32;
    for (int i = tid; i < 1024; i += 256) {
        int r = i >> 5;
        ((float4*)Al)[i] = ((const float4*)A)[(size_t)(m0 + r) * 32 + (i & 31)];
    }
    __syncthreads();

    int tx = tid & 31, ty = tid >> 5;
    int r0 = ty * 4, c0 = tx * 4;
    float acc[4][4] = {};
#pragma unroll 8
    for (int k4 = 0; k4 < 32; ++k4) {
        float4 b0 = *(const float4*)&Wl[(4 * k4 + 0) * 128 + c0];
        float4 b1 = *(const float4*)&Wl[(4 * k4 + 1) * 128 + c0];
        float4 b2 = *(const float4*)&Wl[(4 * k4 + 2) * 128 + c0];
        float4 b3 = *(const float4*)&Wl[(4 * k4 + 3) * 128 + c0];
#pragma unroll
        for (int i = 0; i < 4; ++i) {
            float4 a = *(const float4*)&Al[(r0 + i) * 128 + 4 * k4];
            acc[i][0] += a.x * b0.x + a.y * b1.x + a.z * b2.x + a.w * b3.x;
            acc[i][1] += a.x * b0.y + a.y * b1.y + a.z * b2.y + a.w * b3.y;
            acc[i][2] += a.x * b0.z + a.y * b1.z + a.z * b2.z + a.w * b3.z;
            acc[i][3] += a.x * b0.w + a.y * b1.w + a.z * b2.w + a.w * b3.w;
        }
    }
    float4 bb = *(const float4*)&bias[c0];
    float s[4] = {0.f, 0.f, 0.f, 0.f};
    float q[4] = {0.f, 0.f, 0.f, 0.f};
#pragma unroll
    for (int i = 0; i < 4; ++i) {
        float4 o;
        o.x = fmaxf(acc[i][0] + bb.x, 0.f);
        o.y = fmaxf(acc[i][1] + bb.y, 0.f);
        o.z = fmaxf(acc[i][2] + bb.z, 0.f);
        o.w = fmaxf(acc[i][3] + bb.w, 0.f);
        ((float4*)OUT)[(size_t)(m0 + r0 + i) * 32 + tx] = o;
        s[0] += o.x; q[0] += o.x * o.x;
        s[1] += o.y; q[1] += o.y * o.y;
        s[2] += o.z; q[2] += o.z * o.z;
        s[3] += o.w; q[3] += o.w * o.w;
    }
    __syncthreads();
    float* red = Al;
    *(float4*)&red[ty * 128 + c0] = make_float4(s[0], s[1], s[2], s[3]);
    *(float4*)&red[1024 + ty * 128 + c0] = make_float4(q[0], q[1], q[2], q[3]);
    __syncthreads();
    if (tid < 128) {
        float ss = 0.f, sq = 0.f;
#pragma unroll
        for (int g = 0; g < 8; ++g) {
            ss += red[g * 128 + tid];
            sq += red[1024 + g * 128 + tid];
        }
        unsafeAtomicAdd(&stats[tid], ss);
        unsafeAtomicAdd(&stats[128 + tid], sq);
    }
}

// ============ BN finalize + apply ============
__global__ void k_finalize(const float* __restrict__ stats,
                           const float* __restrict__ gamma,
                           const float* __restrict__ beta,
                           float* __restrict__ ss) {
    int c = threadIdx.x;
    float mean = stats[c] * (1.0f / N_NODES);
    float var = stats[128 + c] * (1.0f / N_NODES) - mean * mean;
    float scale = gamma[c] * rsqrtf(var + 1e-5f);
    ss[c] = scale;
    ss[128 + c] = beta[c] - mean * scale;
}

__global__ __launch_bounds__(256) void k_bn(float4* __restrict__ out,
                                            const float4* __restrict__ ss) {
    int stride = gridDim.x * 256;
    for (int f = blockIdx.x * 256 + threadIdx.x; f < N_NODES * 32; f += stride) {
        int c4 = f & 31;
        float4 sc = ss[c4];
        float4 sh = ss[32 + c4];
        float4 v = out[f];
        v.x = v.x * sc.x + sh.x;
        v.y = v.y * sc.y + sh.y;
        v.z = v.z * sc.z + sh.z;
        v.w = v.w * sc.w + sh.w;
        out[f] = v;
    }
}

extern "C" void kernel_launch(void* const* d_in, const int* in_sizes, int n_in,
                              void* d_out, int out_size, void* d_ws, size_t ws_size,
                              hipStream_t stream) {
    const float* x     = (const float*)d_in[0];
    const int*   ei    = (const int*)d_in[1];
    const float* W1    = (const float*)d_in[2];
    const float* b1    = (const float*)d_in[3];
    const float* W2    = (const float*)d_in[4];
    const float* b2    = (const float*)d_in[5];
    const float* gamma = (const float*)d_in[6];
    const float* beta  = (const float*)d_in[7];
    float* out = (float*)d_out;

    float* agg = (float*)d_ws;                         // 100000*64 f32
    float* h1  = agg + (size_t)N_NODES * D_IN;         // 100000*128 f32
    // CSR scratch aliased INTO the h1 region (dead before k_gemm1 writes h1):
    int* srcs   = (int*)h1;                            // 1.6M ints
    int* counts = srcs + N_EDGES;                      // 100000
    int* loc    = counts + N_NODES;                    // 100000
    int* offs   = loc + N_NODES;                       // 100000
    int* bsum   = offs + N_NODES;                      // 128
    int* bpref  = bsum + 128;                          // 128
    float* stats = h1 + (size_t)N_NODES * D_HID;       // 256
    float* ss    = stats + 256;                        // 256

    const int* src = ei;
    const int* dst = ei + N_EDGES;

    (void)hipMemsetAsync(counts, 0, N_NODES * sizeof(int), stream);
    (void)hipMemsetAsync(stats, 0, 256 * sizeof(float), stream);

    k_hist <<<N_EDGES / 256, 256, 0, stream>>>(dst, counts);
    k_scan1<<<98, 256, 0, stream>>>(counts, loc, bsum);
    k_scan2<<<1, 128, 0, stream>>>(bsum, bpref);
    k_scan3<<<(N_NODES + 255) / 256, 256, 0, stream>>>(loc, bpref, offs);
    k_fill <<<N_EDGES / 256, 256, 0, stream>>>(src, dst, offs, srcs);
    k_gather<<<N_NODES / 4, 256, 0, stream>>>(x, offs, counts, srcs, agg);

    k_gemm1<<<(N_NODES + 63) / 64, 256, 0, stream>>>(agg, W1, b1, h1);
    k_gemm2<<<N_NODES / 32, 256, 80 * 1024, stream>>>(h1, W2, b2, out, stats);
    k_finalize<<<1, 128, 0, stream>>>(stats, gamma, beta, ss);
    k_bn<<<2048, 256, 0, stream>>>((float4*)out, (const float4*)ss);
}

// Round 7
// 447.452 us; speedup vs baseline: 4.0196x; 1.5540x over previous
//
#include <hip/hip_runtime.h>

#define N_NODES 100000
#define N_EDGES 1600000
#define D_IN 64
#define D_HID 128

typedef __attribute__((ext_vector_type(8))) _Float16 half8;
typedef __attribute__((ext_vector_type(4))) float f32x4;

// ============ CSR build ============
__global__ __launch_bounds__(256) void k_hist(const int* __restrict__ dst,
                                              int* __restrict__ counts) {
    int e = blockIdx.x * 256 + threadIdx.x;   // grid = exactly N_EDGES threads
    atomicAdd(&counts[dst[e]], 1);
}

__global__ __launch_bounds__(256) void k_scan1(const int* __restrict__ counts,
                                               int* __restrict__ loc,
                                               int* __restrict__ bsum) {
    __shared__ int tmp[256];
    int t = threadIdx.x;
    int base = blockIdx.x * 1024 + t * 4;
    int v0 = (base + 0 < N_NODES) ? counts[base + 0] : 0;
    int v1 = (base + 1 < N_NODES) ? counts[base + 1] : 0;
    int v2 = (base + 2 < N_NODES) ? counts[base + 2] : 0;
    int v3 = (base + 3 < N_NODES) ? counts[base + 3] : 0;
    tmp[t] = v0 + v1 + v2 + v3;
    __syncthreads();
    for (int off = 1; off < 256; off <<= 1) {
        int val = tmp[t];
        int add = (t >= off) ? tmp[t - off] : 0;
        __syncthreads();
        tmp[t] = val + add;
        __syncthreads();
    }
    int excl = t ? tmp[t - 1] : 0;
    if (base + 0 < N_NODES) loc[base + 0] = excl;
    if (base + 1 < N_NODES) loc[base + 1] = excl + v0;
    if (base + 2 < N_NODES) loc[base + 2] = excl + v0 + v1;
    if (base + 3 < N_NODES) loc[base + 3] = excl + v0 + v1 + v2;
    if (t == 255) bsum[blockIdx.x] = tmp[255];
}

__global__ void k_scan2(const int* __restrict__ bsum, int* __restrict__ bpref) {
    __shared__ int tmp[128];
    int t = threadIdx.x;             // 128 threads
    tmp[t] = (t < 98) ? bsum[t] : 0;
    __syncthreads();
    for (int off = 1; off < 128; off <<= 1) {
        int val = tmp[t];
        int add = (t >= off) ? tmp[t - off] : 0;
        __syncthreads();
        tmp[t] = val + add;
        __syncthreads();
    }
    bpref[t] = t ? tmp[t - 1] : 0;
}

__global__ __launch_bounds__(256) void k_scan3(const int* __restrict__ loc,
                                               const int* __restrict__ bpref,
                                               int* __restrict__ offs) {
    int i = blockIdx.x * 256 + threadIdx.x;
    if (i < N_NODES) offs[i] = loc[i] + bpref[i >> 10];
}

__global__ __launch_bounds__(256) void k_fill(const int* __restrict__ src,
                                              const int* __restrict__ dst,
                                              int* __restrict__ offs,
                                              int* __restrict__ srcs) {
    int e = blockIdx.x * 256 + threadIdx.x;
    int p = atomicAdd(&offs[dst[e]], 1);
    srcs[p] = src[e];
}

// Gather: one wave per node, lane = feature. agg = x[self] + sum x[src]  (fp16 out)
__global__ __launch_bounds__(256) void k_gather(const float* __restrict__ x,
                                                const int* __restrict__ offs_end,
                                                const int* __restrict__ counts,
                                                const int* __restrict__ srcs,
                                                _Float16* __restrict__ aggh) {
    int wid = (blockIdx.x * 256 + threadIdx.x) >> 6;   // 100000 waves exactly
    int lane = threadIdx.x & 63;
    int end = offs_end[wid];
    int beg = end - counts[wid];
    float sum = x[(size_t)wid * 64 + lane];
    int e = beg;
    for (; e + 4 <= end; e += 4) {
        int s0 = srcs[e], s1 = srcs[e + 1], s2 = srcs[e + 2], s3 = srcs[e + 3];
        float a0 = x[(size_t)s0 * 64 + lane];
        float a1 = x[(size_t)s1 * 64 + lane];
        float a2 = x[(size_t)s2 * 64 + lane];
        float a3 = x[(size_t)s3 * 64 + lane];
        sum += a0 + a1 + a2 + a3;
    }
    for (; e < end; ++e) sum += x[(size_t)srcs[e] * 64 + lane];
    aggh[(size_t)wid * 64 + lane] = (_Float16)sum;
}

// ============ Weight pre-pack into fp16 MFMA B-fragment order ============
// slot = (kt*8 + ct)*64 + lane; elem i: W[kt*32 + (lane>>4)*8 + i][ct*16 + (lane&15)]
__global__ __launch_bounds__(256) void k_pack(const float* __restrict__ W1,
                                              const float* __restrict__ W2,
                                              _Float16* __restrict__ W1p,
                                              _Float16* __restrict__ W2p) {
    int t = blockIdx.x * 256 + threadIdx.x;   // 3072 threads
    if (t < 1024) {
        int l = t & 63;
        int row = ((t >> 9) & 1) * 32 + (l >> 4) * 8;
        int col = ((t >> 6) & 7) * 16 + (l & 15);
#pragma unroll
        for (int i = 0; i < 8; ++i)
            W1p[t * 8 + i] = (_Float16)W1[(row + i) * 128 + col];
    } else {
        int s = t - 1024;                     // 0..2047
        int l = s & 63;
        int row = (s >> 9) * 32 + (l >> 4) * 8;
        int col = ((s >> 6) & 7) * 16 + (l & 15);
#pragma unroll
        for (int i = 0; i < 8; ++i)
            W2p[s * 8 + i] = (_Float16)W2[(row + i) * 128 + col];
    }
}

// ============ GEMM1: h1 = relu(agg @ W1 + b1), fp16 MFMA, no LDS ============
// 4 waves/block, 16 rows/wave, 64 rows/block. K=64 (2 k-tiles), N=128 (8 col-tiles).
__global__ __launch_bounds__(256) void k_gemm1(const _Float16* __restrict__ A,
                                               const _Float16* __restrict__ Wp,
                                               const float* __restrict__ bias,
                                               _Float16* __restrict__ H) {
    int lane = threadIdx.x & 63, wv = threadIdx.x >> 6;
    int row0 = blockIdx.x * 64 + wv * 16;
    int ar = row0 + (lane & 15);
    if (ar > N_NODES - 1) ar = N_NODES - 1;
    int ac = (lane >> 4) * 8;
    half8 a0 = *(const half8*)&A[(size_t)ar * 64 + ac];
    half8 a1 = *(const half8*)&A[(size_t)ar * 64 + 32 + ac];
    f32x4 acc[8];
#pragma unroll
    for (int ct = 0; ct < 8; ++ct) {
        half8 w0 = *(const half8*)&Wp[(size_t)(ct * 64 + lane) * 8];
        half8 w1 = *(const half8*)&Wp[(size_t)(512 + ct * 64 + lane) * 8];
        f32x4 c = {0.f, 0.f, 0.f, 0.f};
        c = __builtin_amdgcn_mfma_f32_16x16x32_f16(a0, w0, c, 0, 0, 0);
        c = __builtin_amdgcn_mfma_f32_16x16x32_f16(a1, w1, c, 0, 0, 0);
        acc[ct] = c;
    }
    int g = lane >> 4, cl = lane & 15;
#pragma unroll
    for (int ct = 0; ct < 8; ++ct) {
        int col = ct * 16 + cl;
        float b = bias[col];
#pragma unroll
        for (int r = 0; r < 4; ++r) {
            int row = row0 + g * 4 + r;
            if (row < N_NODES) {
                float v = fmaxf(acc[ct][r] + b, 0.f);
                H[(size_t)row * 128 + col] = (_Float16)v;
            }
        }
    }
}

// ============ GEMM2: out = relu(h1 @ W2 + b2) fp32 + fused BN partial stats =
__global__ __launch_bounds__(256) void k_gemm2(const _Float16* __restrict__ A,
                                               const _Float16* __restrict__ Wp,
                                               const float* __restrict__ bias,
                                               float* __restrict__ OUT,
                                               float* __restrict__ stats) {
    __shared__ float sred[4][256];   // [wave][0..127 = sum, 128..255 = sumsq]
    int lane = threadIdx.x & 63, wv = threadIdx.x >> 6;
    int row0 = blockIdx.x * 64 + wv * 16;
    int ar = row0 + (lane & 15);
    if (ar > N_NODES - 1) ar = N_NODES - 1;
    int ac = (lane >> 4) * 8;
    half8 a[4];
#pragma unroll
    for (int kt = 0; kt < 4; ++kt)
        a[kt] = *(const half8*)&A[(size_t)ar * 128 + kt * 32 + ac];
    int g = lane >> 4, cl = lane & 15;
#pragma unroll
    for (int ct = 0; ct < 8; ++ct) {
        f32x4 c = {0.f, 0.f, 0.f, 0.f};
#pragma unroll
        for (int kt = 0; kt < 4; ++kt) {
            half8 w = *(const half8*)&Wp[(size_t)((kt * 8 + ct) * 64 + lane) * 8];
            c = __builtin_amdgcn_mfma_f32_16x16x32_f16(a[kt], w, c, 0, 0, 0);
        }
        int col = ct * 16 + cl;
        float b = bias[col];
        float s = 0.f, q = 0.f;
#pragma unroll
        for (int r = 0; r < 4; ++r) {
            int row = row0 + g * 4 + r;
            float v = fmaxf(c[r] + b, 0.f);
            if (row < N_NODES) {
                OUT[(size_t)row * 128 + col] = v;
                s += v; q += v * v;
            }
        }
        s += __shfl_xor(s, 16); s += __shfl_xor(s, 32);
        q += __shfl_xor(q, 16); q += __shfl_xor(q, 32);
        if (g == 0) { sred[wv][col] = s; sred[wv][128 + col] = q; }
    }
    __syncthreads();
    int tid = threadIdx.x;
    float v = sred[0][tid] + sred[1][tid] + sred[2][tid] + sred[3][tid];
    unsafeAtomicAdd(&stats[tid], v);
}

// ============ BN finalize + apply ============
__global__ void k_finalize(const float* __restrict__ stats,
                           const float* __restrict__ gamma,
                           const float* __restrict__ beta,
                           float* __restrict__ ss) {
    int c = threadIdx.x;
    float mean = stats[c] * (1.0f / N_NODES);
    float var = stats[128 + c] * (1.0f / N_NODES) - mean * mean;
    float scale = gamma[c] * rsqrtf(var + 1e-5f);
    ss[c] = scale;
    ss[128 + c] = beta[c] - mean * scale;
}

__global__ __launch_bounds__(256) void k_bn(float4* __restrict__ out,
                                            const float4* __restrict__ ss) {
    int stride = gridDim.x * 256;
    for (int f = blockIdx.x * 256 + threadIdx.x; f < N_NODES * 32; f += stride) {
        int c4 = f & 31;
        float4 sc = ss[c4];
        float4 sh = ss[32 + c4];
        float4 v = out[f];
        v.x = v.x * sc.x + sh.x;
        v.y = v.y * sc.y + sh.y;
        v.z = v.z * sc.z + sh.z;
        v.w = v.w * sc.w + sh.w;
        out[f] = v;
    }
}

extern "C" void kernel_launch(void* const* d_in, const int* in_sizes, int n_in,
                              void* d_out, int out_size, void* d_ws, size_t ws_size,
                              hipStream_t stream) {
    const float* x     = (const float*)d_in[0];
    const int*   ei    = (const int*)d_in[1];
    const float* W1    = (const float*)d_in[2];
    const float* b1    = (const float*)d_in[3];
    const float* W2    = (const float*)d_in[4];
    const float* b2    = (const float*)d_in[5];
    const float* gamma = (const float*)d_in[6];
    const float* beta  = (const float*)d_in[7];
    float* out = (float*)d_out;

    char* w = (char*)d_ws;
    _Float16* aggh = (_Float16*)w;  w += (size_t)N_NODES * D_IN * 2;    // 12.8MB
    _Float16* h1h  = (_Float16*)w;  w += (size_t)N_NODES * D_HID * 2;   // 25.6MB
    int* srcs      = (int*)w;       w += (size_t)N_EDGES * 4;           // 6.4MB
    int* counts    = (int*)w;       w += N_NODES * 4;
    int* loc       = (int*)w;       w += N_NODES * 4;
    int* offs      = (int*)w;       w += N_NODES * 4;
    int* bsum      = (int*)w;       w += 512;
    int* bpref     = (int*)w;       w += 512;
    float* stats   = (float*)w;     w += 1024;
    float* ss      = (float*)w;     w += 1024;
    _Float16* W1p  = (_Float16*)w;  w += 16384;
    _Float16* W2p  = (_Float16*)w;  w += 32768;

    const int* src = ei;
    const int* dst = ei + N_EDGES;

    (void)hipMemsetAsync(counts, 0, N_NODES * sizeof(int), stream);
    (void)hipMemsetAsync(stats, 0, 256 * sizeof(float), stream);

    k_pack <<<12, 256, 0, stream>>>(W1, W2, W1p, W2p);
    k_hist <<<N_EDGES / 256, 256, 0, stream>>>(dst, counts);
    k_scan1<<<98, 256, 0, stream>>>(counts, loc, bsum);
    k_scan2<<<1, 128, 0, stream>>>(bsum, bpref);
    k_scan3<<<(N_NODES + 255) / 256, 256, 0, stream>>>(loc, bpref, offs);
    k_fill <<<N_EDGES / 256, 256, 0, stream>>>(src, dst, offs, srcs);
    k_gather<<<N_NODES / 4, 256, 0, stream>>>(x, offs, counts, srcs, aggh);

    k_gemm1<<<(N_NODES + 63) / 64, 256, 0, stream>>>(aggh, W1p, b1, h1h);
    k_gemm2<<<(N_NODES + 63) / 64, 256, 0, stream>>>(h1h, W2p, b2, out, stats);
    k_finalize<<<1, 128, 0, stream>>>(stats, gamma, beta, ss);
    k_bn<<<2048, 256, 0, stream>>>((float4*)out, (const float4*)ss);
}

// Round 10
// 383.502 us; speedup vs baseline: 4.6899x; 1.1668x over previous
//
#include <hip/hip_runtime.h>
#include <hip/hip_fp16.h>

#define N_NODES 100000
#define N_EDGES 1600000
#define D_IN 64
#define D_HID 128
#define NBINS 196          // dst>>9, 512 nodes per bin
#define NBLK 200           // partition blocks
#define EPB 8000           // edges per partition block
#define FCAP 10240         // fine-sort LDS capacity (avg 8163, +23 sigma)

typedef __attribute__((ext_vector_type(8))) _Float16 half8;
typedef __attribute__((ext_vector_type(4))) float f32x4;

__device__ inline float2 h2f(unsigned u) {
    __half2 h = __builtin_bit_cast(__half2, u);
    return __half22float2(h);
}
__device__ inline unsigned f2h(float a, float b) {
    __half2 h = __floats2half2_rn(a, b);
    return __builtin_bit_cast(unsigned, h);
}

// ============ x -> fp16 (packed half2 per 2 cols) ============
__global__ __launch_bounds__(256) void k_xhalf(const float4* __restrict__ x4,
                                               uint2* __restrict__ xh2) {
    int i = blockIdx.x * 256 + threadIdx.x;   // 1.6M exactly
    float4 v = x4[i];
    uint2 o;
    o.x = f2h(v.x, v.y);
    o.y = f2h(v.z, v.w);
    xh2[i] = o;
}

// ============ Partition pass A: per-(block,bin) counts ============
__global__ __launch_bounds__(256) void k_pcount(const int* __restrict__ dst,
                                                int* __restrict__ pbh) {
    __shared__ int hist[NBINS];
    int t = threadIdx.x, b = blockIdx.x;
    if (t < NBINS) hist[t] = 0;
    __syncthreads();
    for (int i = t; i < EPB; i += 256)
        atomicAdd(&hist[dst[b * EPB + i] >> 9], 1);
    __syncthreads();
    if (t < NBINS) pbh[t * NBLK + b] = hist[t];
}

// ============ Partition scan: exclusive over bin-major 196x200 table ========
__global__ void k_pscan(const int* __restrict__ pbh, int* __restrict__ pbo,
                        int* __restrict__ binstart, int* __restrict__ offs) {
    __shared__ int part[256];
    const int TOT = NBINS * NBLK;    // 39200
    int t = threadIdx.x;
    int lo = t * 154, hi = lo + 154 < TOT ? lo + 154 : TOT;
    int s = 0;
    for (int i = lo; i < hi; ++i) s += pbh[i];
    part[t] = s;
    __syncthreads();
    for (int off = 1; off < 256; off <<= 1) {
        int val = part[t];
        int add = (t >= off) ? part[t - off] : 0;
        __syncthreads();
        part[t] = val + add;
        __syncthreads();
    }
    int run = t ? part[t - 1] : 0;
    for (int i = lo; i < hi; ++i) {
        int v = pbh[i];
        pbo[i] = run;
        if ((i % NBLK) == 0) binstart[i / NBLK] = run;
        run += v;
    }
    if (t == 0) { binstart[NBINS] = N_EDGES; offs[N_NODES] = N_EDGES; }
}

// ============ Partition pass B: scatter packed (dstlow<<17|src) ============
__global__ __launch_bounds__(256) void k_pscatter(const int* __restrict__ src,
                                                  const int* __restrict__ dst,
                                                  const int* __restrict__ pbo,
                                                  unsigned* __restrict__ packed) {
    __shared__ int cur[NBINS];
    int t = threadIdx.x, b = blockIdx.x;
    if (t < NBINS) cur[t] = pbo[t * NBLK + b];
    __syncthreads();
    for (int i = t; i < EPB; i += 256) {
        int e = b * EPB + i;
        int d = dst[e];
        int bin = d >> 9;
        int p = atomicAdd(&cur[bin], 1);
        packed[p] = ((unsigned)(d & 511) << 17) | (unsigned)src[e];
    }
}

// ============ Fine sort per bin: emits CSR offs + sorted srcs ============
__global__ __launch_bounds__(256) void k_fsort(const unsigned* __restrict__ packed,
                                               const int* __restrict__ binstart,
                                               int* __restrict__ offs,
                                               int* __restrict__ srcs) {
    __shared__ int nh[512];
    __shared__ int cur[512];
    __shared__ int part[256];
    __shared__ int stage[FCAP];
    int t = threadIdx.x, bin = blockIdx.x;
    int base = binstart[bin];
    int n = binstart[bin + 1] - base;
    nh[t] = 0; nh[t + 256] = 0;
    __syncthreads();
    for (int i = t; i < n; i += 256)
        atomicAdd(&nh[packed[base + i] >> 17], 1);
    __syncthreads();
    int a0 = nh[2 * t], a1 = nh[2 * t + 1];
    part[t] = a0 + a1;
    __syncthreads();
    for (int off = 1; off < 256; off <<= 1) {
        int val = part[t];
        int add = (t >= off) ? part[t - off] : 0;
        __syncthreads();
        part[t] = val + add;
        __syncthreads();
    }
    int excl = t ? part[t - 1] : 0;
    cur[2 * t] = excl;
    cur[2 * t + 1] = excl + a0;
    // CSR row pointers
    int node0 = bin * 512 + 2 * t;
    if (node0 < N_NODES) offs[node0] = base + excl;
    if (node0 + 1 < N_NODES) offs[node0 + 1] = base + excl + a0;
    __syncthreads();
    for (int i = t; i < n; i += 256) {
        unsigned u = packed[base + i];
        int dl = u >> 17;
        int s = u & 0x1FFFF;
        int p = atomicAdd(&cur[dl], 1);
        if (p < FCAP) stage[p] = s;
        else srcs[base + p] = s;   // overflow fallback (correct, ~never taken)
    }
    __syncthreads();
    int m = n < FCAP ? n : FCAP;
    for (int i = t; i < m; i += 256) srcs[base + i] = stage[i];
}

// ============ Gather: wave=node, half-waves process edge pairs (fp16 x) ====
__global__ __launch_bounds__(256) void k_gather(const unsigned* __restrict__ xh,
                                                const int* __restrict__ offs,
                                                const int* __restrict__ srcs,
                                                unsigned* __restrict__ aggh) {
    int wid = (blockIdx.x * 256 + threadIdx.x) >> 6;   // node
    int lane = threadIdx.x & 63;
    int half = lane >> 5, c = lane & 31;
    int beg = offs[wid], end = offs[wid + 1];
    float2 sum;
    if (half == 0) sum = h2f(xh[(size_t)wid * 32 + c]);
    else sum = make_float2(0.f, 0.f);
    int e = beg;
    for (; e + 4 <= end; e += 4) {
        int i0 = e + half, i1 = e + 2 + half;
        int s0 = srcs[i0], s1 = srcs[i1];
        float2 v0 = h2f(xh[(size_t)s0 * 32 + c]);
        float2 v1 = h2f(xh[(size_t)s1 * 32 + c]);
        sum.x += v0.x + v1.x;
        sum.y += v0.y + v1.y;
    }
    for (; e < end; e += 2) {
        int idx = e + half;
        if (idx < end) {
            float2 v = h2f(xh[(size_t)srcs[idx] * 32 + c]);
            sum.x += v.x; sum.y += v.y;
        }
    }
    sum.x += __shfl_xor(sum.x, 32);
    sum.y += __shfl_xor(sum.y, 32);
    if (half == 0) aggh[(size_t)wid * 32 + c] = f2h(sum.x, sum.y);
}

// ============ Weight pre-pack into fp16 MFMA B-fragment order ============
__global__ __launch_bounds__(256) void k_pack(const float* __restrict__ W1,
                                              const float* __restrict__ W2,
                                              _Float16* __restrict__ W1p,
                                              _Float16* __restrict__ W2p) {
    int t = blockIdx.x * 256 + threadIdx.x;   // 3072 threads
    if (t < 1024) {
        int l = t & 63;
        int row = ((t >> 9) & 1) * 32 + (l >> 4) * 8;
        int col = ((t >> 6) & 7) * 16 + (l & 15);
#pragma unroll
        for (int i = 0; i < 8; ++i)
            W1p[t * 8 + i] = (_Float16)W1[(row + i) * 128 + col];
    } else {
        int s = t - 1024;                     // 0..2047
        int l = s & 63;
        int row = (s >> 9) * 32 + (l >> 4) * 8;
        int col = ((s >> 6) & 7) * 16 + (l & 15);
#pragma unroll
        for (int i = 0; i < 8; ++i)
            W2p[s * 8 + i] = (_Float16)W2[(row + i) * 128 + col];
    }
}

// ============ GEMM1: h1 = relu(agg @ W1 + b1), fp16 MFMA, no LDS ============
__global__ __launch_bounds__(256) void k_gemm1(const _Float16* __restrict__ A,
                                               const _Float16* __restrict__ Wp,
                                               const float* __restrict__ bias,
                                               _Float16* __restrict__ H) {
    int lane = threadIdx.x & 63, wv = threadIdx.x >> 6;
    int row0 = blockIdx.x * 64 + wv * 16;
    int ar = row0 + (lane & 15);
    if (ar > N_NODES - 1) ar = N_NODES - 1;
    int ac = (lane >> 4) * 8;
    half8 a0 = *(const half8*)&A[(size_t)ar * 64 + ac];
    half8 a1 = *(const half8*)&A[(size_t)ar * 64 + 32 + ac];
    f32x4 acc[8];
#pragma unroll
    for (int ct = 0; ct < 8; ++ct) {
        half8 w0 = *(const half8*)&Wp[(size_t)(ct * 64 + lane) * 8];
        half8 w1 = *(const half8*)&Wp[(size_t)(512 + ct * 64 + lane) * 8];
        f32x4 c = {0.f, 0.f, 0.f, 0.f};
        c = __builtin_amdgcn_mfma_f32_16x16x32_f16(a0, w0, c, 0, 0, 0);
        c = __builtin_amdgcn_mfma_f32_16x16x32_f16(a1, w1, c, 0, 0, 0);
        acc[ct] = c;
    }
    int g = lane >> 4, cl = lane & 15;
#pragma unroll
    for (int ct = 0; ct < 8; ++ct) {
        int col = ct * 16 + cl;
        float b = bias[col];
#pragma unroll
        for (int r = 0; r < 4; ++r) {
            int row = row0 + g * 4 + r;
            if (row < N_NODES) {
                float v = fmaxf(acc[ct][r] + b, 0.f);
                H[(size_t)row * 128 + col] = (_Float16)v;
            }
        }
    }
}

// ============ GEMM2: out = relu(h1 @ W2 + b2) fp32 + fused BN partial stats =
__global__ __launch_bounds__(256) void k_gemm2(const _Float16* __restrict__ A,
                                               const _Float16* __restrict__ Wp,
                                               const float* __restrict__ bias,
                                               float* __restrict__ OUT,
                                               float* __restrict__ stats) {
    __shared__ float sred[4][256];   // [wave][0..127 = sum, 128..255 = sumsq]
    int lane = threadIdx.x & 63, wv = threadIdx.x >> 6;
    int row0 = blockIdx.x * 64 + wv * 16;
    int ar = row0 + (lane & 15);
    if (ar > N_NODES - 1) ar = N_NODES - 1;
    int ac = (lane >> 4) * 8;
    half8 a[4];
#pragma unroll
    for (int kt = 0; kt < 4; ++kt)
        a[kt] = *(const half8*)&A[(size_t)ar * 128 + kt * 32 + ac];
    int g = lane >> 4, cl = lane & 15;
#pragma unroll
    for (int ct = 0; ct < 8; ++ct) {
        f32x4 c = {0.f, 0.f, 0.f, 0.f};
#pragma unroll
        for (int kt = 0; kt < 4; ++kt) {
            half8 w = *(const half8*)&Wp[(size_t)((kt * 8 + ct) * 64 + lane) * 8];
            c = __builtin_amdgcn_mfma_f32_16x16x32_f16(a[kt], w, c, 0, 0, 0);
        }
        int col = ct * 16 + cl;
        float b = bias[col];
        float s = 0.f, q = 0.f;
#pragma unroll
        for (int r = 0; r < 4; ++r) {
            int row = row0 + g * 4 + r;
            float v = fmaxf(c[r] + b, 0.f);
            if (row < N_NODES) {
                OUT[(size_t)row * 128 + col] = v;
                s += v; q += v * v;
            }
        }
        s += __shfl_xor(s, 16); s += __shfl_xor(s, 32);
        q += __shfl_xor(q, 16); q += __shfl_xor(q, 32);
        if (g == 0) { sred[wv][col] = s; sred[wv][128 + col] = q; }
    }
    __syncthreads();
    int tid = threadIdx.x;
    float v = sred[0][tid] + sred[1][tid] + sred[2][tid] + sred[3][tid];
    unsafeAtomicAdd(&stats[tid], v);
}

// ============ BN finalize + apply ============
__global__ void k_finalize(const float* __restrict__ stats,
                           const float* __restrict__ gamma,
                           const float* __restrict__ beta,
                           float* __restrict__ ss) {
    int c = threadIdx.x;
    float mean = stats[c] * (1.0f / N_NODES);
    float var = stats[128 + c] * (1.0f / N_NODES) - mean * mean;
    float scale = gamma[c] * rsqrtf(var + 1e-5f);
    ss[c] = scale;
    ss[128 + c] = beta[c] - mean * scale;
}

__global__ __launch_bounds__(256) void k_bn(float4* __restrict__ out,
                                            const float4* __restrict__ ss) {
    int stride = gridDim.x * 256;
    for (int f = blockIdx.x * 256 + threadIdx.x; f < N_NODES * 32; f += stride) {
        int c4 = f & 31;
        float4 sc = ss[c4];
        float4 sh = ss[32 + c4];
        float4 v = out[f];
        v.x = v.x * sc.x + sh.x;
        v.y = v.y * sc.y + sh.y;
        v.z = v.z * sc.z + sh.z;
        v.w = v.w * sc.w + sh.w;
        out[f] = v;
    }
}

extern "C" void kernel_launch(void* const* d_in, const int* in_sizes, int n_in,
                              void* d_out, int out_size, void* d_ws, size_t ws_size,
                              hipStream_t stream) {
    const float* x     = (const float*)d_in[0];
    const int*   ei    = (const int*)d_in[1];
    const float* W1    = (const float*)d_in[2];
    const float* b1    = (const float*)d_in[3];
    const float* W2    = (const float*)d_in[4];
    const float* b2    = (const float*)d_in[5];
    const float* gamma = (const float*)d_in[6];
    const float* beta  = (const float*)d_in[7];
    float* out = (float*)d_out;

    char* w = (char*)d_ws;
    unsigned* xh   = (unsigned*)w;  w += (size_t)N_NODES * 32 * 4;      // 12.8MB
    unsigned* aggh = (unsigned*)w;  w += (size_t)N_NODES * 32 * 4;      // 12.8MB
    _Float16* h1h  = (_Float16*)w;  w += (size_t)N_NODES * D_HID * 2;   // 25.6MB
    unsigned* packed = (unsigned*)w; w += (size_t)N_EDGES * 4;          // 6.4MB
    int* srcs      = (int*)w;       w += (size_t)N_EDGES * 4;           // 6.4MB
    int* offs      = (int*)w;       w += (N_NODES + 1) * 4;
    int* pbh       = (int*)w;       w += NBINS * NBLK * 4;
    int* pbo       = (int*)w;       w += NBINS * NBLK * 4;
    int* binstart  = (int*)w;       w += (NBINS + 1) * 4;
    float* stats   = (float*)w;     w += 1024;
    float* ss      = (float*)w;     w += 1024;
    _Float16* W1p  = (_Float16*)w;  w += 16384;
    _Float16* W2p  = (_Float16*)w;  w += 32768;

    const int* src = ei;
    const int* dst = ei + N_EDGES;

    (void)hipMemsetAsync(stats, 0, 256 * sizeof(float), stream);

    k_pack    <<<12, 256, 0, stream>>>(W1, W2, W1p, W2p);
    k_xhalf   <<<N_NODES * 64 / 4 / 256, 256, 0, stream>>>((const float4*)x, (uint2*)xh);
    k_pcount  <<<NBLK, 256, 0, stream>>>(dst, pbh);
    k_pscan   <<<1, 256, 0, stream>>>(pbh, pbo, binstart, offs);
    k_pscatter<<<NBLK, 256, 0, stream>>>(src, dst, pbo, packed);
    k_fsort   <<<NBINS, 256, 0, stream>>>(packed, binstart, offs, srcs);
    k_gather  <<<N_NODES / 4, 256, 0, stream>>>(xh, offs, srcs, aggh);

    k_gemm1<<<(N_NODES + 63) / 64, 256, 0, stream>>>((const _Float16*)aggh, W1p, b1, h1h);
    k_gemm2<<<(N_NODES + 63) / 64, 256, 0, stream>>>(h1h, W2p, b2, out, stats);
    k_finalize<<<1, 128, 0, stream>>>(stats, gamma, beta, ss);
    k_bn<<<2048, 256, 0, stream>>>((float4*)out, (const float4*)ss);
}

// Round 11
// 362.449 us; speedup vs baseline: 4.9623x; 1.0581x over previous
//
#include <hip/hip_runtime.h>
#include <hip/hip_fp16.h>

#define N_NODES 100000
#define N_EDGES 1600000
#define D_IN 64
#define D_HID 128
#define NBINS 196          // dst>>9, 512 nodes per bin
#define NBLK 200           // partition blocks
#define EPB 8000           // edges per partition block
#define FCAP 10240         // fine-sort LDS capacity (avg 8163, +23 sigma)
#define LROW 136           // LDS h1 row stride (fp16 elems): 2-way banks only

typedef __attribute__((ext_vector_type(8))) _Float16 half8;
typedef __attribute__((ext_vector_type(4))) float f32x4;

__device__ inline float2 h2f(unsigned u) {
    __half2 h = __builtin_bit_cast(__half2, u);
    return __half22float2(h);
}
__device__ inline unsigned f2h(float a, float b) {
    __half2 h = __floats2half2_rn(a, b);
    return __builtin_bit_cast(unsigned, h);
}

// ============ x -> fp16 (packed half2 per 2 cols) ============
__global__ __launch_bounds__(256) void k_xhalf(const float4* __restrict__ x4,
                                               uint2* __restrict__ xh2) {
    int i = blockIdx.x * 256 + threadIdx.x;   // 1.6M exactly
    float4 v = x4[i];
    uint2 o;
    o.x = f2h(v.x, v.y);
    o.y = f2h(v.z, v.w);
    xh2[i] = o;
}

// ============ Partition pass A: per-(block,bin) counts ============
__global__ __launch_bounds__(256) void k_pcount(const int* __restrict__ dst,
                                                int* __restrict__ pbh) {
    __shared__ int hist[NBINS];
    int t = threadIdx.x, b = blockIdx.x;
    if (t < NBINS) hist[t] = 0;
    __syncthreads();
    for (int i = t; i < EPB; i += 256)
        atomicAdd(&hist[dst[b * EPB + i] >> 9], 1);
    __syncthreads();
    if (t < NBINS) pbh[t * NBLK + b] = hist[t];
}

// ============ Partition scan: exclusive over bin-major 196x200 table ========
__global__ void k_pscan(const int* __restrict__ pbh, int* __restrict__ pbo,
                        int* __restrict__ binstart, int* __restrict__ offs) {
    __shared__ int part[256];
    const int TOT = NBINS * NBLK;    // 39200
    int t = threadIdx.x;
    int lo = t * 154, hi = lo + 154 < TOT ? lo + 154 : TOT;
    int s = 0;
    for (int i = lo; i < hi; ++i) s += pbh[i];
    part[t] = s;
    __syncthreads();
    for (int off = 1; off < 256; off <<= 1) {
        int val = part[t];
        int add = (t >= off) ? part[t - off] : 0;
        __syncthreads();
        part[t] = val + add;
        __syncthreads();
    }
    int run = t ? part[t - 1] : 0;
    for (int i = lo; i < hi; ++i) {
        int v = pbh[i];
        pbo[i] = run;
        if ((i % NBLK) == 0) binstart[i / NBLK] = run;
        run += v;
    }
    if (t == 0) { binstart[NBINS] = N_EDGES; offs[N_NODES] = N_EDGES; }
}

// ============ Partition pass B: scatter packed (dstlow<<17|src) ============
__global__ __launch_bounds__(256) void k_pscatter(const int* __restrict__ src,
                                                  const int* __restrict__ dst,
                                                  const int* __restrict__ pbo,
                                                  unsigned* __restrict__ packed) {
    __shared__ int cur[NBINS];
    int t = threadIdx.x, b = blockIdx.x;
    if (t < NBINS) cur[t] = pbo[t * NBLK + b];
    __syncthreads();
    for (int i = t; i < EPB; i += 256) {
        int e = b * EPB + i;
        int d = dst[e];
        int bin = d >> 9;
        int p = atomicAdd(&cur[bin], 1);
        packed[p] = ((unsigned)(d & 511) << 17) | (unsigned)src[e];
    }
}

// ============ Fine sort per bin: emits CSR offs + sorted srcs ============
__global__ __launch_bounds__(256) void k_fsort(const unsigned* __restrict__ packed,
                                               const int* __restrict__ binstart,
                                               int* __restrict__ offs,
                                               int* __restrict__ srcs) {
    __shared__ int nh[512];
    __shared__ int cur[512];
    __shared__ int part[256];
    __shared__ int stage[FCAP];
    int t = threadIdx.x, bin = blockIdx.x;
    int base = binstart[bin];
    int n = binstart[bin + 1] - base;
    nh[t] = 0; nh[t + 256] = 0;
    __syncthreads();
    for (int i = t; i < n; i += 256)
        atomicAdd(&nh[packed[base + i] >> 17], 1);
    __syncthreads();
    int a0 = nh[2 * t], a1 = nh[2 * t + 1];
    part[t] = a0 + a1;
    __syncthreads();
    for (int off = 1; off < 256; off <<= 1) {
        int val = part[t];
        int add = (t >= off) ? part[t - off] : 0;
        __syncthreads();
        part[t] = val + add;
        __syncthreads();
    }
    int excl = t ? part[t - 1] : 0;
    cur[2 * t] = excl;
    cur[2 * t + 1] = excl + a0;
    // CSR row pointers
    int node0 = bin * 512 + 2 * t;
    if (node0 < N_NODES) offs[node0] = base + excl;
    if (node0 + 1 < N_NODES) offs[node0 + 1] = base + excl + a0;
    __syncthreads();
    for (int i = t; i < n; i += 256) {
        unsigned u = packed[base + i];
        int dl = u >> 17;
        int s = u & 0x1FFFF;
        int p = atomicAdd(&cur[dl], 1);
        if (p < FCAP) stage[p] = s;
        else srcs[base + p] = s;   // overflow fallback (correct, ~never taken)
    }
    __syncthreads();
    int m = n < FCAP ? n : FCAP;
    for (int i = t; i < m; i += 256) srcs[base + i] = stage[i];
}

// ============ Gather: wave=node, half-waves process edge pairs (fp16 x) ====
__global__ __launch_bounds__(256) void k_gather(const unsigned* __restrict__ xh,
                                                const int* __restrict__ offs,
                                                const int* __restrict__ srcs,
                                                unsigned* __restrict__ aggh) {
    int wid = (blockIdx.x * 256 + threadIdx.x) >> 6;   // node
    int lane = threadIdx.x & 63;
    int half = lane >> 5, c = lane & 31;
    int beg = offs[wid], end = offs[wid + 1];
    float2 sum;
    if (half == 0) sum = h2f(xh[(size_t)wid * 32 + c]);
    else sum = make_float2(0.f, 0.f);
    int e = beg;
    for (; e + 4 <= end; e += 4) {
        int i0 = e + half, i1 = e + 2 + half;
        int s0 = srcs[i0], s1 = srcs[i1];
        float2 v0 = h2f(xh[(size_t)s0 * 32 + c]);
        float2 v1 = h2f(xh[(size_t)s1 * 32 + c]);
        sum.x += v0.x + v1.x;
        sum.y += v0.y + v1.y;
    }
    for (; e < end; e += 2) {
        int idx = e + half;
        if (idx < end) {
            float2 v = h2f(xh[(size_t)srcs[idx] * 32 + c]);
            sum.x += v.x; sum.y += v.y;
        }
    }
    sum.x += __shfl_xor(sum.x, 32);
    sum.y += __shfl_xor(sum.y, 32);
    if (half == 0) aggh[(size_t)wid * 32 + c] = f2h(sum.x, sum.y);
}

// ============ Weight pre-pack into fp16 MFMA B-fragment order ============
__global__ __launch_bounds__(256) void k_pack(const float* __restrict__ W1,
                                              const float* __restrict__ W2,
                                              _Float16* __restrict__ W1p,
                                              _Float16* __restrict__ W2p) {
    int t = blockIdx.x * 256 + threadIdx.x;   // 3072 threads
    if (t < 1024) {
        int l = t & 63;
        int row = ((t >> 9) & 1) * 32 + (l >> 4) * 8;
        int col = ((t >> 6) & 7) * 16 + (l & 15);
#pragma unroll
        for (int i = 0; i < 8; ++i)
            W1p[t * 8 + i] = (_Float16)W1[(row + i) * 128 + col];
    } else {
        int s = t - 1024;                     // 0..2047
        int l = s & 63;
        int row = (s >> 9) * 32 + (l >> 4) * 8;
        int col = ((s >> 6) & 7) * 16 + (l & 15);
#pragma unroll
        for (int i = 0; i < 8; ++i)
            W2p[s * 8 + i] = (_Float16)W2[(row + i) * 128 + col];
    }
}

// ============ Fused MLP: outh = relu(relu(agg@W1+b1)@W2+b2) fp16 + BN stats =
// 4 waves x 16 rows. h1 tile parked in LDS (row stride 136 -> 2-way banks).
__global__ __launch_bounds__(256) void k_mlp(const _Float16* __restrict__ A,
                                             const _Float16* __restrict__ W1p,
                                             const float* __restrict__ b1,
                                             const _Float16* __restrict__ W2p,
                                             const float* __restrict__ b2,
                                             _Float16* __restrict__ OUTH,
                                             float* __restrict__ stats) {
    __shared__ _Float16 h1l[4][16 * LROW];
    __shared__ float sred[4][256];
    int lane = threadIdx.x & 63, wv = threadIdx.x >> 6;
    int row0 = blockIdx.x * 64 + wv * 16;
    int ar = row0 + (lane & 15);
    if (ar > N_NODES - 1) ar = N_NODES - 1;
    int ac = (lane >> 4) * 8;
    int g = lane >> 4, cl = lane & 15;

    // ---- GEMM1: 16x64 @ 64x128 ----
    half8 a0 = *(const half8*)&A[(size_t)ar * 64 + ac];
    half8 a1 = *(const half8*)&A[(size_t)ar * 64 + 32 + ac];
#pragma unroll
    for (int ct = 0; ct < 8; ++ct) {
        half8 w0 = *(const half8*)&W1p[(size_t)(ct * 64 + lane) * 8];
        half8 w1 = *(const half8*)&W1p[(size_t)(512 + ct * 64 + lane) * 8];
        f32x4 c = {0.f, 0.f, 0.f, 0.f};
        c = __builtin_amdgcn_mfma_f32_16x16x32_f16(a0, w0, c, 0, 0, 0);
        c = __builtin_amdgcn_mfma_f32_16x16x32_f16(a1, w1, c, 0, 0, 0);
        float b = b1[ct * 16 + cl];
#pragma unroll
        for (int r = 0; r < 4; ++r) {
            float v = fmaxf(c[r] + b, 0.f);
            h1l[wv][(g * 4 + r) * LROW + ct * 16 + cl] = (_Float16)v;
        }
    }
    __syncthreads();

    // ---- GEMM2: 16x128 @ 128x128 ----
    half8 a2[4];
#pragma unroll
    for (int kt = 0; kt < 4; ++kt)
        a2[kt] = *(const half8*)&h1l[wv][(lane & 15) * LROW + kt * 32 + ac];
#pragma unroll
    for (int ct = 0; ct < 8; ++ct) {
        f32x4 c = {0.f, 0.f, 0.f, 0.f};
#pragma unroll
        for (int kt = 0; kt < 4; ++kt) {
            half8 w = *(const half8*)&W2p[(size_t)((kt * 8 + ct) * 64 + lane) * 8];
            c = __builtin_amdgcn_mfma_f32_16x16x32_f16(a2[kt], w, c, 0, 0, 0);
        }
        int col = ct * 16 + cl;
        float b = b2[col];
        float s = 0.f, q = 0.f;
#pragma unroll
        for (int r = 0; r < 4; ++r) {
            int row = row0 + g * 4 + r;
            float v = fmaxf(c[r] + b, 0.f);
            if (row < N_NODES) {
                OUTH[(size_t)row * 128 + col] = (_Float16)v;
                s += v; q += v * v;
            }
        }
        s += __shfl_xor(s, 16); s += __shfl_xor(s, 32);
        q += __shfl_xor(q, 16); q += __shfl_xor(q, 32);
        if (g == 0) { sred[wv][col] = s; sred[wv][128 + col] = q; }
    }
    __syncthreads();
    int tid = threadIdx.x;
    float v = sred[0][tid] + sred[1][tid] + sred[2][tid] + sred[3][tid];
    unsafeAtomicAdd(&stats[tid], v);
}

// ============ BN finalize + apply ============
__global__ void k_finalize(const float* __restrict__ stats,
                           const float* __restrict__ gamma,
                           const float* __restrict__ beta,
                           float* __restrict__ ss) {
    int c = threadIdx.x;
    float mean = stats[c] * (1.0f / N_NODES);
    float var = stats[128 + c] * (1.0f / N_NODES) - mean * mean;
    float scale = gamma[c] * rsqrtf(var + 1e-5f);
    ss[c] = scale;
    ss[128 + c] = beta[c] - mean * scale;
}

// Read fp16 pre-BN, write fp32 normalized output.
__global__ __launch_bounds__(256) void k_bn(const uint2* __restrict__ outh,
                                            float4* __restrict__ out,
                                            const float4* __restrict__ ss) {
    int stride = gridDim.x * 256;
    for (int f = blockIdx.x * 256 + threadIdx.x; f < N_NODES * 32; f += stride) {
        int c4 = f & 31;
        float4 sc = ss[c4];
        float4 sh = ss[32 + c4];
        uint2 u = outh[f];
        float2 lo = h2f(u.x), hi = h2f(u.y);
        float4 v;
        v.x = lo.x * sc.x + sh.x;
        v.y = lo.y * sc.y + sh.y;
        v.z = hi.x * sc.z + sh.z;
        v.w = hi.y * sc.w + sh.w;
        out[f] = v;
    }
}

extern "C" void kernel_launch(void* const* d_in, const int* in_sizes, int n_in,
                              void* d_out, int out_size, void* d_ws, size_t ws_size,
                              hipStream_t stream) {
    const float* x     = (const float*)d_in[0];
    const int*   ei    = (const int*)d_in[1];
    const float* W1    = (const float*)d_in[2];
    const float* b1    = (const float*)d_in[3];
    const float* W2    = (const float*)d_in[4];
    const float* b2    = (const float*)d_in[5];
    const float* gamma = (const float*)d_in[6];
    const float* beta  = (const float*)d_in[7];
    float* out = (float*)d_out;

    char* w = (char*)d_ws;
    unsigned* xh   = (unsigned*)w;  w += (size_t)N_NODES * 32 * 4;      // 12.8MB
    unsigned* aggh = (unsigned*)w;  w += (size_t)N_NODES * 32 * 4;      // 12.8MB
    _Float16* outh = (_Float16*)w;  w += (size_t)N_NODES * D_HID * 2;   // 25.6MB
    unsigned* packed = (unsigned*)w; w += (size_t)N_EDGES * 4;          // 6.4MB
    int* srcs      = (int*)w;       w += (size_t)N_EDGES * 4;           // 6.4MB
    int* offs      = (int*)w;       w += (N_NODES + 1) * 4;
    int* pbh       = (int*)w;       w += NBINS * NBLK * 4;
    int* pbo       = (int*)w;       w += NBINS * NBLK * 4;
    int* binstart  = (int*)w;       w += (NBINS + 1) * 4;
    float* stats   = (float*)w;     w += 1024;
    float* ss      = (float*)w;     w += 1024;
    _Float16* W1p  = (_Float16*)w;  w += 16384;
    _Float16* W2p  = (_Float16*)w;  w += 32768;

    const int* src = ei;
    const int* dst = ei + N_EDGES;

    (void)hipMemsetAsync(stats, 0, 256 * sizeof(float), stream);

    k_pack    <<<12, 256, 0, stream>>>(W1, W2, W1p, W2p);
    k_xhalf   <<<N_NODES * 64 / 4 / 256, 256, 0, stream>>>((const float4*)x, (uint2*)xh);
    k_pcount  <<<NBLK, 256, 0, stream>>>(dst, pbh);
    k_pscan   <<<1, 256, 0, stream>>>(pbh, pbo, binstart, offs);
    k_pscatter<<<NBLK, 256, 0, stream>>>(src, dst, pbo, packed);
    k_fsort   <<<NBINS, 256, 0, stream>>>(packed, binstart, offs, srcs);
    k_gather  <<<N_NODES / 4, 256, 0, stream>>>(xh, offs, srcs, aggh);

    k_mlp<<<(N_NODES + 63) / 64, 256, 0, stream>>>((const _Float16*)aggh,
                                                   W1p, b1, W2p, b2, outh, stats);
    k_finalize<<<1, 128, 0, stream>>>(stats, gamma, beta, ss);
    k_bn<<<2048, 256, 0, stream>>>((const uint2*)outh, (float4*)out, (const float4*)ss);
}